// Round 13
// baseline (404.860 us; speedup 1.0000x reference)
//
#include <hip/hip_runtime.h>
#include <stdint.h>

// GraphPropLayer on MI355X — round 13: persistent-grid k_fused (1024 blocks,
// global tile work-stealing kills inter-block tail; was 37% occupancy);
// k_proj+k_fill merged into one dispatch (fill atomics hide under proj MFMA).
//
// Fragment layout (v_mfma_f32_16x16x32_f16):
//   A (16m x 32k): lane = row + 16*((k%32)/8), elem j = k%8
//   B (32k x 16n): lane = col + 16*((k%32)/8), elem j = k%8
//   C/D: col = lane&15, row = (lane>>4)*4 + reg
// Tile = 512 halfs (1 KB); buffers indexed [(mt_or_nt * KT + kt)*512 + lane*8 + j].

#define NN 50000
#define NE 512000
#define SCAN_N (2 * NN)
#define SCAN_BLOCKS ((SCAN_N + 1023) / 1024)  // 98
#define NTILES 1563

typedef unsigned short u16;
typedef unsigned int u32;
using h2  = __attribute__((ext_vector_type(2))) _Float16;
using h4  = __attribute__((ext_vector_type(4))) _Float16;
using h8  = __attribute__((ext_vector_type(8))) _Float16;
using f4v = __attribute__((ext_vector_type(4))) float;

__device__ __forceinline__ float h2f(u16 u) {
  _Float16 h; __builtin_memcpy(&h, &u, 2); return (float)h;
}
__device__ __forceinline__ u16 f2h(float f) {
  _Float16 h = (_Float16)f; u16 u; __builtin_memcpy(&u, &h, 2); return u;
}

// ---------------- fused prep kernel (+hist) ----------------
// blocks [0,512): Wcat | [512,1280): Gcat | [1280,1472): Whh | [1472,1474): vbias
// | [1474,4599): nsh | [4599,6599): hist
__global__ __launch_bounds__(256) void k_prep(
    const float* __restrict__ Wf1, const float* __restrict__ bf1,
    const float* __restrict__ Wr1, const float* __restrict__ br1,
    const float* __restrict__ W_ih, const float* __restrict__ Wf2,
    const float* __restrict__ Wr2, const float* __restrict__ W_hh,
    const float* __restrict__ bf2, const float* __restrict__ br2,
    const float* __restrict__ ns,
    const int* __restrict__ from, const int* __restrict__ to,
    u16* __restrict__ Wc16, float* __restrict__ biascat,
    u16* __restrict__ G16, u16* __restrict__ Wh16,
    float* __restrict__ vf, float* __restrict__ vr,
    u16* __restrict__ nsf, int* __restrict__ cnt) {
  const int b = blockIdx.x, tid = threadIdx.x;
  if (b < 512) {
    // Wcat fragment (64 nt x 4 kt). Logical col c:
    // [0,256): Wf1[:,0:128](+bf1) | [256,512): Wr1[:,128:256] |
    // [512,768): Wf1[:,128:256]   | [768,1024): Wr1[:,0:128](+br1)
    int c = b * 2 + (tid >> 7);
    int k = tid & 127;
    const float* src;
    if (c < 256)      src = Wf1 + (size_t)c * 256;
    else if (c < 512) src = Wr1 + (size_t)(c - 256) * 256 + 128;
    else if (c < 768) src = Wf1 + (size_t)(c - 512) * 256 + 128;
    else              src = Wr1 + (size_t)(c - 768) * 256;
    float v = src[k];
    int nt = c >> 4, kt = k >> 5, g = (k & 31) >> 3, j = k & 7;
    int lane = (c & 15) + g * 16;
    Wc16[((size_t)nt * 4 + kt) * 512 + lane * 8 + j] = f2h(v);
    if (k == 0) biascat[c] = (c < 256) ? bf1[c] : ((c >= 768) ? br1[c - 768] : 0.f);
  } else if (b < 1280) {
    // Gcat fragment (24 nt x 16 kt)
    int bb = b - 512;
    int c = bb % 384, w = bb / 384;
    const float* W2 = w ? Wr2 : Wf2;
    int k = tid;
    float acc = 0.f;
    for (int o = 0; o < 256; ++o)
      acc = fmaf(W_ih[(size_t)c * 256 + o], W2[(size_t)o * 256 + k], acc);
    int kg = w * 256 + k;
    int nt = c >> 4, kt = kg >> 5, g = (kg & 31) >> 3, j = kg & 7;
    int lane = (c & 15) + g * 16;
    G16[((size_t)nt * 16 + kt) * 512 + lane * 8 + j] = f2h(acc);
  } else if (b < 1472) {
    // W_hh fragment (24 nt x 4 kt)
    int c = (b - 1280) * 2 + (tid >> 7);
    int k = tid & 127;
    float v = W_hh[(size_t)c * 128 + k];
    int nt = c >> 4, kt = k >> 5, g = (k & 31) >> 3, j = k & 7;
    int lane = (c & 15) + g * 16;
    Wh16[((size_t)nt * 4 + kt) * 512 + lane * 8 + j] = f2h(v);
  } else if (b < 1474) {
    int c = (b - 1472) * 256 + tid;
    if (c < 384) {
      float a = 0.f, bb = 0.f;
      for (int o = 0; o < 256; ++o) {
        float w = W_ih[(size_t)c * 256 + o];
        a = fmaf(w, bf2[o], a);
        bb = fmaf(w, br2[o], bb);
      }
      vf[c] = a; vr[c] = bb;
    }
  } else if (b < 4599) {
    // ns -> fp16 A-fragment (3125 mt x 4 kt)
    int t = (b - 1474) * 256 + tid;
    int n = t >> 4, kk8 = t & 15;
    float4 v0 = *(const float4*)(ns + (size_t)n * 128 + kk8 * 8);
    float4 v1 = *(const float4*)(ns + (size_t)n * 128 + kk8 * 8 + 4);
    u16 hv[8] = {f2h(v0.x), f2h(v0.y), f2h(v0.z), f2h(v0.w),
                 f2h(v1.x), f2h(v1.y), f2h(v1.z), f2h(v1.w)};
    int mt = n >> 4, r = n & 15, kt = kk8 >> 2, g = kk8 & 3;
    int lane = r + g * 16;
    *(uint4*)(nsf + ((size_t)mt * 4 + kt) * 512 + lane * 8) = *(const uint4*)hv;
  } else {
    // degree histogram
    int e = (b - 4599) * 256 + tid;
    if (e < NE) {
      atomicAdd(cnt + to[e], 1);
      atomicAdd(cnt + NN + from[e], 1);
    }
  }
}

// ---------------- CSR build ----------------
__global__ __launch_bounds__(256) void k_scanA(const int* __restrict__ cnt,
                                               int* __restrict__ bsum) {
  __shared__ int part[256];
  int b = blockIdx.x, tid = threadIdx.x;
  int idx = b * 1024 + tid * 4;
  int s = 0;
  if (idx + 3 < SCAN_N) {
    int4 v = *(const int4*)(cnt + idx);
    s = v.x + v.y + v.z + v.w;
  } else {
    for (int q = 0; q < 4; ++q)
      if (idx + q < SCAN_N) s += cnt[idx + q];
  }
  part[tid] = s;
  __syncthreads();
  for (int d = 128; d > 0; d >>= 1) {
    if (tid < d) part[tid] += part[tid + d];
    __syncthreads();
  }
  if (tid == 0) bsum[b] = part[0];
}

// scanC with inline bsum prefix
__global__ __launch_bounds__(256) void k_scanC(const int* __restrict__ cnt,
                                               const int* __restrict__ bsum,
                                               int* __restrict__ off,
                                               int* __restrict__ cur) {
  __shared__ int part[256];
  __shared__ int bs[SCAN_BLOCKS];
  int b = blockIdx.x, tid = threadIdx.x;
  if (tid < SCAN_BLOCKS) bs[tid] = bsum[tid];
  int idx = b * 1024 + tid * 4;
  int c[4] = {0, 0, 0, 0};
  if (idx + 3 < SCAN_N) {
    int4 v = *(const int4*)(cnt + idx);
    c[0] = v.x; c[1] = v.y; c[2] = v.z; c[3] = v.w;
  } else {
    for (int q = 0; q < 4; ++q)
      if (idx + q < SCAN_N) c[q] = cnt[idx + q];
  }
  int s = c[0] + c[1] + c[2] + c[3];
  part[tid] = s;
  __syncthreads();
  for (int d = 1; d < 256; d <<= 1) {
    int x = (tid >= d) ? part[tid - d] : 0;
    __syncthreads();
    part[tid] += x;
    __syncthreads();
  }
  int pre = 0;
  for (int j = 0; j < b; ++j) pre += bs[j];
  int run = pre + ((tid > 0) ? part[tid - 1] : 0);
#pragma unroll
  for (int q = 0; q < 4; ++q) {
    if (idx + q < SCAN_N) {
      off[idx + q] = run;
      cur[idx + q] = run;
      run += c[q];
    }
  }
  if (b == 0 && tid == 0) off[SCAN_N] = 2 * NE;
}

// ---------------- merged: CSR fill + MFMA projection ----------------
// blocks [0,2000): fill (atomic/latency-heavy, issued first) |
// [2000, 5128): proj (bx = bb%782, by = bb/782)
__global__ __launch_bounds__(256) void k_projfill(
    const u16* __restrict__ nsf, const u16* __restrict__ Wc16,
    const float* __restrict__ biascat,
    u16* __restrict__ Tin, u16* __restrict__ Tnode, u16* __restrict__ Tout,
    const int* __restrict__ from, const int* __restrict__ to,
    int* __restrict__ cur, int* __restrict__ nbr) {
  const int b = blockIdx.x;
  if (b < 2000) {
    int e = b * 256 + threadIdx.x;
    if (e < NE) {
      int f = from[e], t = to[e];
      nbr[atomicAdd(cur + t, 1)] = f;
      nbr[atomicAdd(cur + NN + f, 1)] = t;
    }
    return;
  }
  const int bb = b - 2000;
  const int bx = bb % 782, by = bb / 782;
  const int w = threadIdx.x >> 6, lane = threadIdx.x & 63;
  const int mt0 = bx * 4;
  const int nt0 = by * 16 + w * 4;
  const h8 hzv = {(_Float16)0.f, (_Float16)0.f, (_Float16)0.f, (_Float16)0.f,
                  (_Float16)0.f, (_Float16)0.f, (_Float16)0.f, (_Float16)0.f};
  f4v acc[4][4];
#pragma unroll
  for (int m = 0; m < 4; ++m)
#pragma unroll
    for (int n = 0; n < 4; ++n) acc[m][n] = (f4v){0.f, 0.f, 0.f, 0.f};

#pragma unroll
  for (int kt = 0; kt < 4; ++kt) {
    h8 a[4], bfr[4];
#pragma unroll
    for (int m = 0; m < 4; ++m) {
      int mt = mt0 + m;
      a[m] = (mt < 3125) ? *(const h8*)(nsf + ((size_t)mt * 4 + kt) * 512 + lane * 8) : hzv;
    }
#pragma unroll
    for (int n = 0; n < 4; ++n)
      bfr[n] = *(const h8*)(Wc16 + ((size_t)(nt0 + n) * 4 + kt) * 512 + lane * 8);
#pragma unroll
    for (int m = 0; m < 4; ++m)
#pragma unroll
      for (int n = 0; n < 4; ++n)
        acc[m][n] = __builtin_amdgcn_mfma_f32_16x16x32_f16(a[m], bfr[n], acc[m][n], 0, 0, 0);
  }

  const int c0 = lane & 15, rB = (lane >> 4) * 4;
#pragma unroll
  for (int n = 0; n < 4; ++n) {
    const int ntg = nt0 + n;
    u16* dst;
    size_t stride;
    int col;
    if (ntg < 16)      { dst = Tin;   stride = 256; col = ntg * 16 + c0; }
    else if (ntg < 48) { dst = Tnode; stride = 512; col = (ntg - 16) * 16 + c0; }
    else               { dst = Tout;  stride = 256; col = (ntg - 48) * 16 + c0; }
    float bias = biascat[ntg * 16 + c0];
#pragma unroll
    for (int m = 0; m < 4; ++m) {
      int mt = mt0 + m;
      if (mt >= 3125) continue;
#pragma unroll
      for (int reg = 0; reg < 4; ++reg) {
        int row = mt * 16 + rB + reg;
        dst[(size_t)row * stride + col] = f2h(acc[m][n][reg] + bias);
      }
    }
  }
}

// ---------------- K2+K3 fused, persistent grid + global work-stealing ----------------
// 1024 blocks (4/CU) loop over 1563 mt-pair tiles via gctr. Per tile: gather
// (64 tasks, LDS work-steal) -> swizzled LDS Sf -> step A (pre-barrier) ->
// step B + epilogue -> trailing barrier (protects sfl reuse).
__global__ __launch_bounds__(512) void k_fused(const u16* __restrict__ Tin,
                                               const u16* __restrict__ Tnode,
                                               const u16* __restrict__ Tout,
                                               const int* __restrict__ nbr,
                                               const int* __restrict__ off,
                                               const u16* __restrict__ nsf,
                                               const u16* __restrict__ G16,
                                               const u16* __restrict__ Wh16,
                                               const float* __restrict__ ns,
                                               const float* __restrict__ b_ih,
                                               const float* __restrict__ b_hh,
                                               const float* __restrict__ vf,
                                               const float* __restrict__ vr,
                                               int* __restrict__ gctr,
                                               float* __restrict__ out) {
  __shared__ __align__(16) u16 sfl[2 * 16 * 512];  // 32 KB
  __shared__ int ctr;
  __shared__ int tile_s;
  const int wid = threadIdx.x >> 6, lane = threadIdx.x & 63;
  const h2 z2 = {(_Float16)0.f, (_Float16)0.f};
  const int g = (lane & 7) >> 1, j0 = (lane & 1) * 4;
  const h8 hz = {(_Float16)0.f, (_Float16)0.f, (_Float16)0.f, (_Float16)0.f,
                 (_Float16)0.f, (_Float16)0.f, (_Float16)0.f, (_Float16)0.f};

  for (;;) {
    if (threadIdx.x == 0) {
      tile_s = atomicAdd(gctr, 1);
      ctr = 0;
    }
    __syncthreads();
    const int tile = tile_s;
    if (tile >= NTILES) break;
    const int mt0 = tile * 2;
    const bool has1 = (mt0 + 1) < 3125;

    // ---- gather phase: work-stealing over 64 (node,dir) tasks ----
#define LOADF(q_, kbase_) \
  (*(const h4*)(gtab + (size_t)__builtin_amdgcn_readlane(nb, (kbase_) + (q_)) * 256 + lane * 4))
#define CONSUME(wvq_)                                           \
  {                                                             \
    h2 t01 = {(wvq_)[0], (wvq_)[1]};                            \
    h2 t23 = {(wvq_)[2], (wvq_)[3]};                            \
    t01 = __builtin_elementwise_max(t01 + inv01, z2);           \
    t23 = __builtin_elementwise_max(t23 + inv23, z2);           \
    a0 += (float)t01[0]; a1 += (float)t01[1];                   \
    a2 += (float)t23[0]; a3 += (float)t23[1];                   \
  }
    for (;;) {
      int t0 = 0;
      if (lane == 0) t0 = atomicAdd(&ctr, 1);
      const int task = __shfl(t0, 0);
      if (task >= 64) break;
      const int nn = task >> 1, dir = task & 1;
      const int n = mt0 * 16 + nn;
      if (n >= NN) continue;
      const u16* gtab = dir ? Tout : Tin;
      const int invofs = dir ? 0 : 256;
      h4 invv = __builtin_nontemporal_load(
          (const h4*)(Tnode + (size_t)n * 512 + invofs + lane * 4));
      h2 inv01 = {invv[0], invv[1]};
      h2 inv23 = {invv[2], invv[3]};
      const int s = off[dir * NN + n];
      const int e = off[dir * NN + n + 1];
      float a0 = 0.f, a1 = 0.f, a2 = 0.f, a3 = 0.f;
      for (int i = s; i < e; i += 64) {
        int nb = (i + lane < e) ? __builtin_nontemporal_load(nbr + i + lane) : 0;
        int cnt = min(64, e - i);
        int k = 0;
        for (; k + 7 < cnt; k += 8) {
          h4 w0 = LOADF(0, k), w1 = LOADF(1, k), w2 = LOADF(2, k), w3 = LOADF(3, k);
          h4 w4 = LOADF(4, k), w5 = LOADF(5, k), w6 = LOADF(6, k), w7 = LOADF(7, k);
          CONSUME(w0) CONSUME(w1) CONSUME(w2) CONSUME(w3)
          CONSUME(w4) CONSUME(w5) CONSUME(w6) CONSUME(w7)
        }
        if (k + 3 < cnt) {
          h4 w0 = LOADF(0, k), w1 = LOADF(1, k), w2 = LOADF(2, k), w3 = LOADF(3, k);
          CONSUME(w0) CONSUME(w1) CONSUME(w2) CONSUME(w3)
          k += 4;
        }
        for (; k < cnt; ++k) {
          h4 w0 = LOADF(0, k);
          CONSUME(w0)
        }
      }
      const int m = nn >> 4, r = nn & 15;
      const int kt = dir * 8 + (lane >> 3);
      const int laneF = r + g * 16;
      const int slot = laneF ^ (lane >> 3);  // XOR-swizzle vs kt&7 (= lane>>3)
      u16 hv[4] = {f2h(a0), f2h(a1), f2h(a2), f2h(a3)};
      *(ushort4*)(sfl + ((m * 16 + kt) * 512) + slot * 8 + j0) = *(const ushort4*)hv;
    }
#undef LOADF
#undef CONSUME

    // ---- step A (no Sf dependency — overlaps gather stragglers) ----
    const int base = wid;
    f4v gh[2][3], gi[2][3];
#pragma unroll
    for (int m = 0; m < 2; ++m)
#pragma unroll
      for (int gg = 0; gg < 3; ++gg) {
        gh[m][gg] = (f4v){0.f, 0.f, 0.f, 0.f};
        gi[m][gg] = (f4v){0.f, 0.f, 0.f, 0.f};
      }
#pragma unroll
    for (int kt = 0; kt < 4; ++kt) {
      h8 a0 = *(const h8*)(nsf + ((size_t)mt0 * 4 + kt) * 512 + lane * 8);
      h8 a1 = has1 ? *(const h8*)(nsf + ((size_t)(mt0 + 1) * 4 + kt) * 512 + lane * 8) : hz;
#pragma unroll
      for (int gg = 0; gg < 3; ++gg) {
        h8 b = *(const h8*)(Wh16 + ((size_t)(base + 8 * gg) * 4 + kt) * 512 + lane * 8);
        gh[0][gg] = __builtin_amdgcn_mfma_f32_16x16x32_f16(a0, b, gh[0][gg], 0, 0, 0);
        gh[1][gg] = __builtin_amdgcn_mfma_f32_16x16x32_f16(a1, b, gh[1][gg], 0, 0, 0);
      }
    }

    __syncthreads();

    // ---- step B: gi = S @ Gcat.T (K=512), A from swizzled LDS ----
#pragma unroll
    for (int kt = 0; kt < 16; ++kt) {
      const int slot = lane ^ (kt & 7);
      h8 a0 = *(const h8*)(sfl + (0 * 16 + kt) * 512 + slot * 8);
      h8 a1 = has1 ? *(const h8*)(sfl + (1 * 16 + kt) * 512 + slot * 8) : hz;
#pragma unroll
      for (int gg = 0; gg < 3; ++gg) {
        h8 b = *(const h8*)(G16 + ((size_t)(base + 8 * gg) * 16 + kt) * 512 + lane * 8);
        gi[0][gg] = __builtin_amdgcn_mfma_f32_16x16x32_f16(a0, b, gi[0][gg], 0, 0, 0);
        gi[1][gg] = __builtin_amdgcn_mfma_f32_16x16x32_f16(a1, b, gi[1][gg], 0, 0, 0);
      }
    }

    // ---- epilogue ----
    const int c0 = lane & 15, rB = (lane >> 4) * 4;
    const int d = base * 16 + c0;
    const float vf0 = vf[d], vf1 = vf[128 + d], vf2 = vf[256 + d];
    const float vr0 = vr[d], vr1 = vr[128 + d], vr2 = vr[256 + d];
    const float bi0 = b_ih[d], bi1 = b_ih[128 + d], bi2 = b_ih[256 + d];
    const float bh0 = b_hh[d], bh1 = b_hh[128 + d], bh2 = b_hh[256 + d];
#pragma unroll
    for (int m = 0; m < 2; ++m) {
      if (m == 1 && !has1) continue;
      const int mt = mt0 + m;
#pragma unroll
      for (int reg = 0; reg < 4; ++reg) {
        int row = mt * 16 + rB + reg;
        float idg = (float)(off[row + 1] - off[row]);
        float odg = (float)(off[NN + row + 1] - off[NN + row]);
        float gr = gi[m][0][reg] + idg * vf0 + odg * vr0 + bi0;
        float gz = gi[m][1][reg] + idg * vf1 + odg * vr1 + bi1;
        float gn = gi[m][2][reg] + idg * vf2 + odg * vr2 + bi2;
        float hr = gh[m][0][reg] + bh0;
        float hzv = gh[m][1][reg] + bh1;
        float hn = gh[m][2][reg] + bh2;
        float rg = 1.f / (1.f + __expf(-(gr + hr)));
        float zg = 1.f / (1.f + __expf(-(gz + hzv)));
        float ng = tanhf(gn + rg * hn);
        float h = ns[(size_t)row * 128 + d];
        out[(size_t)row * 128 + d] = (1.f - zg) * ng + zg * h;
      }
    }

    __syncthreads();  // protect sfl before next tile's gather overwrites it
  }
}

// ---------------- launch ----------------
extern "C" void kernel_launch(void* const* d_in, const int* in_sizes, int n_in,
                              void* d_out, int out_size, void* d_ws, size_t ws_size,
                              hipStream_t stream) {
  const float* ns   = (const float*)d_in[0];
  const int* from   = (const int*)d_in[1];
  const int* to     = (const int*)d_in[2];
  const float* Wf1  = (const float*)d_in[3];
  const float* bf1  = (const float*)d_in[4];
  const float* Wf2  = (const float*)d_in[5];
  const float* bf2  = (const float*)d_in[6];
  const float* Wr1  = (const float*)d_in[7];
  const float* br1  = (const float*)d_in[8];
  const float* Wr2  = (const float*)d_in[9];
  const float* br2  = (const float*)d_in[10];
  const float* W_ih = (const float*)d_in[11];
  const float* W_hh = (const float*)d_in[12];
  const float* b_ih = (const float*)d_in[13];
  const float* b_hh = (const float*)d_in[14];
  float* out = (float*)d_out;

  // workspace layout (256B aligned)
  char* w = (char*)d_ws;
  u16*   Wc16    = (u16*)(w + 0);            // 262144
  float* biascat = (float*)(w + 262144);     // 4096
  u16*   G16     = (u16*)(w + 266240);       // 393216
  u16*   Wh16    = (u16*)(w + 659456);       // 98304
  float* vf      = (float*)(w + 757760);     // 1536
  float* vr      = (float*)(w + 759296);     // 1536
  int*   gctr    = (int*)(w + 760832);       // 256 (zeroed with cnt)
  int*   cnt     = (int*)(w + 761088);       // 400128
  int*   off     = (int*)(w + 1161216);      // 400128
  int*   cur     = (int*)(w + 1561344);      // 400128
  int*   bsum    = (int*)(w + 1961472);      // 512
  int*   nbr     = (int*)(w + 1961984);      // 4096000
  u16*   nsf     = (u16*)(w + 6057984);      // 12800000
  u16*   Tin     = (u16*)(w + 18857984);     // 25600000
  u16*   Tout    = (u16*)(w + 44457984);     // 25600000
  u16*   Tnode   = (u16*)(w + 70057984);     // 51200000
  // total 121257984 bytes

  hipMemsetAsync(w + 760832, 0, 256 + 400000, stream);  // gctr + cnt

  k_prep<<<6599, 256, 0, stream>>>(Wf1, bf1, Wr1, br1, W_ih, Wf2, Wr2, W_hh,
                                   bf2, br2, ns, from, to, Wc16, biascat, G16,
                                   Wh16, vf, vr, nsf, cnt);

  k_scanA<<<SCAN_BLOCKS, 256, 0, stream>>>(cnt, bsum);
  k_scanC<<<SCAN_BLOCKS, 256, 0, stream>>>(cnt, bsum, off, cur);

  k_projfill<<<5128, 256, 0, stream>>>(nsf, Wc16, biascat, Tin, Tnode, Tout,
                                       from, to, cur, nbr);

  k_fused<<<1024, 512, 0, stream>>>(Tin, Tnode, Tout, nbr, off, nsf, G16, Wh16,
                                    ns, b_ih, b_hh, vf, vr, gctr, out);
}

// Round 14
// 328.352 us; speedup vs baseline: 1.2330x; 1.2330x over previous
//
#include <hip/hip_runtime.h>
#include <stdint.h>

// GraphPropLayer on MI355X — round 14: revert persistent grid (116 VGPR killed
// occupancy, 238µs); k_fused back to round-12 form (1563 blocks, 48 VGPR).
// Keep round-13's projfill merge (6 dispatches).
//
// Fragment layout (v_mfma_f32_16x16x32_f16):
//   A (16m x 32k): lane = row + 16*((k%32)/8), elem j = k%8
//   B (32k x 16n): lane = col + 16*((k%32)/8), elem j = k%8
//   C/D: col = lane&15, row = (lane>>4)*4 + reg
// Tile = 512 halfs (1 KB); buffers indexed [(mt_or_nt * KT + kt)*512 + lane*8 + j].

#define NN 50000
#define NE 512000
#define SCAN_N (2 * NN)
#define SCAN_BLOCKS ((SCAN_N + 1023) / 1024)  // 98

typedef unsigned short u16;
typedef unsigned int u32;
using h2  = __attribute__((ext_vector_type(2))) _Float16;
using h4  = __attribute__((ext_vector_type(4))) _Float16;
using h8  = __attribute__((ext_vector_type(8))) _Float16;
using f4v = __attribute__((ext_vector_type(4))) float;

__device__ __forceinline__ float h2f(u16 u) {
  _Float16 h; __builtin_memcpy(&h, &u, 2); return (float)h;
}
__device__ __forceinline__ u16 f2h(float f) {
  _Float16 h = (_Float16)f; u16 u; __builtin_memcpy(&u, &h, 2); return u;
}

// ---------------- fused prep kernel (+hist) ----------------
// blocks [0,512): Wcat | [512,1280): Gcat | [1280,1472): Whh | [1472,1474): vbias
// | [1474,4599): nsh | [4599,6599): hist
__global__ __launch_bounds__(256) void k_prep(
    const float* __restrict__ Wf1, const float* __restrict__ bf1,
    const float* __restrict__ Wr1, const float* __restrict__ br1,
    const float* __restrict__ W_ih, const float* __restrict__ Wf2,
    const float* __restrict__ Wr2, const float* __restrict__ W_hh,
    const float* __restrict__ bf2, const float* __restrict__ br2,
    const float* __restrict__ ns,
    const int* __restrict__ from, const int* __restrict__ to,
    u16* __restrict__ Wc16, float* __restrict__ biascat,
    u16* __restrict__ G16, u16* __restrict__ Wh16,
    float* __restrict__ vf, float* __restrict__ vr,
    u16* __restrict__ nsf, int* __restrict__ cnt) {
  const int b = blockIdx.x, tid = threadIdx.x;
  if (b < 512) {
    // Wcat fragment (64 nt x 4 kt). Logical col c:
    // [0,256): Wf1[:,0:128](+bf1) | [256,512): Wr1[:,128:256] |
    // [512,768): Wf1[:,128:256]   | [768,1024): Wr1[:,0:128](+br1)
    int c = b * 2 + (tid >> 7);
    int k = tid & 127;
    const float* src;
    if (c < 256)      src = Wf1 + (size_t)c * 256;
    else if (c < 512) src = Wr1 + (size_t)(c - 256) * 256 + 128;
    else if (c < 768) src = Wf1 + (size_t)(c - 512) * 256 + 128;
    else              src = Wr1 + (size_t)(c - 768) * 256;
    float v = src[k];
    int nt = c >> 4, kt = k >> 5, g = (k & 31) >> 3, j = k & 7;
    int lane = (c & 15) + g * 16;
    Wc16[((size_t)nt * 4 + kt) * 512 + lane * 8 + j] = f2h(v);
    if (k == 0) biascat[c] = (c < 256) ? bf1[c] : ((c >= 768) ? br1[c - 768] : 0.f);
  } else if (b < 1280) {
    // Gcat fragment (24 nt x 16 kt)
    int bb = b - 512;
    int c = bb % 384, w = bb / 384;
    const float* W2 = w ? Wr2 : Wf2;
    int k = tid;
    float acc = 0.f;
    for (int o = 0; o < 256; ++o)
      acc = fmaf(W_ih[(size_t)c * 256 + o], W2[(size_t)o * 256 + k], acc);
    int kg = w * 256 + k;
    int nt = c >> 4, kt = kg >> 5, g = (kg & 31) >> 3, j = kg & 7;
    int lane = (c & 15) + g * 16;
    G16[((size_t)nt * 16 + kt) * 512 + lane * 8 + j] = f2h(acc);
  } else if (b < 1472) {
    // W_hh fragment (24 nt x 4 kt)
    int c = (b - 1280) * 2 + (tid >> 7);
    int k = tid & 127;
    float v = W_hh[(size_t)c * 128 + k];
    int nt = c >> 4, kt = k >> 5, g = (k & 31) >> 3, j = k & 7;
    int lane = (c & 15) + g * 16;
    Wh16[((size_t)nt * 4 + kt) * 512 + lane * 8 + j] = f2h(v);
  } else if (b < 1474) {
    int c = (b - 1472) * 256 + tid;
    if (c < 384) {
      float a = 0.f, bb = 0.f;
      for (int o = 0; o < 256; ++o) {
        float w = W_ih[(size_t)c * 256 + o];
        a = fmaf(w, bf2[o], a);
        bb = fmaf(w, br2[o], bb);
      }
      vf[c] = a; vr[c] = bb;
    }
  } else if (b < 4599) {
    // ns -> fp16 A-fragment (3125 mt x 4 kt)
    int t = (b - 1474) * 256 + tid;
    int n = t >> 4, kk8 = t & 15;
    float4 v0 = *(const float4*)(ns + (size_t)n * 128 + kk8 * 8);
    float4 v1 = *(const float4*)(ns + (size_t)n * 128 + kk8 * 8 + 4);
    u16 hv[8] = {f2h(v0.x), f2h(v0.y), f2h(v0.z), f2h(v0.w),
                 f2h(v1.x), f2h(v1.y), f2h(v1.z), f2h(v1.w)};
    int mt = n >> 4, r = n & 15, kt = kk8 >> 2, g = kk8 & 3;
    int lane = r + g * 16;
    *(uint4*)(nsf + ((size_t)mt * 4 + kt) * 512 + lane * 8) = *(const uint4*)hv;
  } else {
    // degree histogram
    int e = (b - 4599) * 256 + tid;
    if (e < NE) {
      atomicAdd(cnt + to[e], 1);
      atomicAdd(cnt + NN + from[e], 1);
    }
  }
}

// ---------------- CSR build ----------------
__global__ __launch_bounds__(256) void k_scanA(const int* __restrict__ cnt,
                                               int* __restrict__ bsum) {
  __shared__ int part[256];
  int b = blockIdx.x, tid = threadIdx.x;
  int idx = b * 1024 + tid * 4;
  int s = 0;
  if (idx + 3 < SCAN_N) {
    int4 v = *(const int4*)(cnt + idx);
    s = v.x + v.y + v.z + v.w;
  } else {
    for (int q = 0; q < 4; ++q)
      if (idx + q < SCAN_N) s += cnt[idx + q];
  }
  part[tid] = s;
  __syncthreads();
  for (int d = 128; d > 0; d >>= 1) {
    if (tid < d) part[tid] += part[tid + d];
    __syncthreads();
  }
  if (tid == 0) bsum[b] = part[0];
}

// scanC with inline bsum prefix
__global__ __launch_bounds__(256) void k_scanC(const int* __restrict__ cnt,
                                               const int* __restrict__ bsum,
                                               int* __restrict__ off,
                                               int* __restrict__ cur) {
  __shared__ int part[256];
  __shared__ int bs[SCAN_BLOCKS];
  int b = blockIdx.x, tid = threadIdx.x;
  if (tid < SCAN_BLOCKS) bs[tid] = bsum[tid];
  int idx = b * 1024 + tid * 4;
  int c[4] = {0, 0, 0, 0};
  if (idx + 3 < SCAN_N) {
    int4 v = *(const int4*)(cnt + idx);
    c[0] = v.x; c[1] = v.y; c[2] = v.z; c[3] = v.w;
  } else {
    for (int q = 0; q < 4; ++q)
      if (idx + q < SCAN_N) c[q] = cnt[idx + q];
  }
  int s = c[0] + c[1] + c[2] + c[3];
  part[tid] = s;
  __syncthreads();
  for (int d = 1; d < 256; d <<= 1) {
    int x = (tid >= d) ? part[tid - d] : 0;
    __syncthreads();
    part[tid] += x;
    __syncthreads();
  }
  int pre = 0;
  for (int j = 0; j < b; ++j) pre += bs[j];
  int run = pre + ((tid > 0) ? part[tid - 1] : 0);
#pragma unroll
  for (int q = 0; q < 4; ++q) {
    if (idx + q < SCAN_N) {
      off[idx + q] = run;
      cur[idx + q] = run;
      run += c[q];
    }
  }
  if (b == 0 && tid == 0) off[SCAN_N] = 2 * NE;
}

// ---------------- merged: CSR fill + MFMA projection ----------------
// blocks [0,2000): fill (atomic/latency-heavy, issued first) |
// [2000, 5128): proj (bx = bb%782, by = bb/782)
__global__ __launch_bounds__(256) void k_projfill(
    const u16* __restrict__ nsf, const u16* __restrict__ Wc16,
    const float* __restrict__ biascat,
    u16* __restrict__ Tin, u16* __restrict__ Tnode, u16* __restrict__ Tout,
    const int* __restrict__ from, const int* __restrict__ to,
    int* __restrict__ cur, int* __restrict__ nbr) {
  const int b = blockIdx.x;
  if (b < 2000) {
    int e = b * 256 + threadIdx.x;
    if (e < NE) {
      int f = from[e], t = to[e];
      nbr[atomicAdd(cur + t, 1)] = f;
      nbr[atomicAdd(cur + NN + f, 1)] = t;
    }
    return;
  }
  const int bb = b - 2000;
  const int bx = bb % 782, by = bb / 782;
  const int w = threadIdx.x >> 6, lane = threadIdx.x & 63;
  const int mt0 = bx * 4;
  const int nt0 = by * 16 + w * 4;
  const h8 hzv = {(_Float16)0.f, (_Float16)0.f, (_Float16)0.f, (_Float16)0.f,
                  (_Float16)0.f, (_Float16)0.f, (_Float16)0.f, (_Float16)0.f};
  f4v acc[4][4];
#pragma unroll
  for (int m = 0; m < 4; ++m)
#pragma unroll
    for (int n = 0; n < 4; ++n) acc[m][n] = (f4v){0.f, 0.f, 0.f, 0.f};

#pragma unroll
  for (int kt = 0; kt < 4; ++kt) {
    h8 a[4], bfr[4];
#pragma unroll
    for (int m = 0; m < 4; ++m) {
      int mt = mt0 + m;
      a[m] = (mt < 3125) ? *(const h8*)(nsf + ((size_t)mt * 4 + kt) * 512 + lane * 8) : hzv;
    }
#pragma unroll
    for (int n = 0; n < 4; ++n)
      bfr[n] = *(const h8*)(Wc16 + ((size_t)(nt0 + n) * 4 + kt) * 512 + lane * 8);
#pragma unroll
    for (int m = 0; m < 4; ++m)
#pragma unroll
      for (int n = 0; n < 4; ++n)
        acc[m][n] = __builtin_amdgcn_mfma_f32_16x16x32_f16(a[m], bfr[n], acc[m][n], 0, 0, 0);
  }

  const int c0 = lane & 15, rB = (lane >> 4) * 4;
#pragma unroll
  for (int n = 0; n < 4; ++n) {
    const int ntg = nt0 + n;
    u16* dst;
    size_t stride;
    int col;
    if (ntg < 16)      { dst = Tin;   stride = 256; col = ntg * 16 + c0; }
    else if (ntg < 48) { dst = Tnode; stride = 512; col = (ntg - 16) * 16 + c0; }
    else               { dst = Tout;  stride = 256; col = (ntg - 48) * 16 + c0; }
    float bias = biascat[ntg * 16 + c0];
#pragma unroll
    for (int m = 0; m < 4; ++m) {
      int mt = mt0 + m;
      if (mt >= 3125) continue;
#pragma unroll
      for (int reg = 0; reg < 4; ++reg) {
        int row = mt * 16 + rB + reg;
        dst[(size_t)row * stride + col] = f2h(acc[m][n][reg] + bias);
      }
    }
  }
}

// ---------------- K2+K3 fused: gather (-> swizzled LDS Sf) + GRU ----------------
// Round-12 form: one mt-pair per block (grid 1563), 8 waves, block-local
// work-stealing, step A hoisted before the barrier.
__global__ __launch_bounds__(512) void k_fused(const u16* __restrict__ Tin,
                                               const u16* __restrict__ Tnode,
                                               const u16* __restrict__ Tout,
                                               const int* __restrict__ nbr,
                                               const int* __restrict__ off,
                                               const u16* __restrict__ nsf,
                                               const u16* __restrict__ G16,
                                               const u16* __restrict__ Wh16,
                                               const float* __restrict__ ns,
                                               const float* __restrict__ b_ih,
                                               const float* __restrict__ b_hh,
                                               const float* __restrict__ vf,
                                               const float* __restrict__ vr,
                                               float* __restrict__ out) {
  __shared__ __align__(16) u16 sfl[2 * 16 * 512];  // 32 KB
  __shared__ int ctr;
  const int wid = threadIdx.x >> 6, lane = threadIdx.x & 63;
  const int mt0 = blockIdx.x * 2;
  const bool has1 = (mt0 + 1) < 3125;
  const h2 z2 = {(_Float16)0.f, (_Float16)0.f};

  if (threadIdx.x == 0) ctr = 0;
  __syncthreads();

  // ---- gather phase: work-stealing over 64 (node,dir) tasks ----
  const int g = (lane & 7) >> 1, j0 = (lane & 1) * 4;
#define LOADF(q_, kbase_) \
  (*(const h4*)(gtab + (size_t)__builtin_amdgcn_readlane(nb, (kbase_) + (q_)) * 256 + lane * 4))
#define CONSUME(wvq_)                                           \
  {                                                             \
    h2 t01 = {(wvq_)[0], (wvq_)[1]};                            \
    h2 t23 = {(wvq_)[2], (wvq_)[3]};                            \
    t01 = __builtin_elementwise_max(t01 + inv01, z2);           \
    t23 = __builtin_elementwise_max(t23 + inv23, z2);           \
    a0 += (float)t01[0]; a1 += (float)t01[1];                   \
    a2 += (float)t23[0]; a3 += (float)t23[1];                   \
  }
  for (;;) {
    int t0 = 0;
    if (lane == 0) t0 = atomicAdd(&ctr, 1);
    const int task = __shfl(t0, 0);
    if (task >= 64) break;
    const int nn = task >> 1, dir = task & 1;
    const int n = mt0 * 16 + nn;
    if (n >= NN) continue;
    const u16* gtab = dir ? Tout : Tin;
    const int invofs = dir ? 0 : 256;
    h4 invv = __builtin_nontemporal_load(
        (const h4*)(Tnode + (size_t)n * 512 + invofs + lane * 4));
    h2 inv01 = {invv[0], invv[1]};
    h2 inv23 = {invv[2], invv[3]};
    const int s = off[dir * NN + n];
    const int e = off[dir * NN + n + 1];
    float a0 = 0.f, a1 = 0.f, a2 = 0.f, a3 = 0.f;
    for (int i = s; i < e; i += 64) {
      int nb = (i + lane < e) ? __builtin_nontemporal_load(nbr + i + lane) : 0;
      int cnt = min(64, e - i);
      int k = 0;
      for (; k + 7 < cnt; k += 8) {
        h4 w0 = LOADF(0, k), w1 = LOADF(1, k), w2 = LOADF(2, k), w3 = LOADF(3, k);
        h4 w4 = LOADF(4, k), w5 = LOADF(5, k), w6 = LOADF(6, k), w7 = LOADF(7, k);
        CONSUME(w0) CONSUME(w1) CONSUME(w2) CONSUME(w3)
        CONSUME(w4) CONSUME(w5) CONSUME(w6) CONSUME(w7)
      }
      if (k + 3 < cnt) {
        h4 w0 = LOADF(0, k), w1 = LOADF(1, k), w2 = LOADF(2, k), w3 = LOADF(3, k);
        CONSUME(w0) CONSUME(w1) CONSUME(w2) CONSUME(w3)
        k += 4;
      }
      for (; k < cnt; ++k) {
        h4 w0 = LOADF(0, k);
        CONSUME(w0)
      }
    }
    const int m = nn >> 4, r = nn & 15;
    const int kt = dir * 8 + (lane >> 3);
    const int laneF = r + g * 16;
    const int slot = laneF ^ (lane >> 3);  // XOR-swizzle vs kt&7 (= lane>>3)
    u16 hv[4] = {f2h(a0), f2h(a1), f2h(a2), f2h(a3)};
    *(ushort4*)(sfl + ((m * 16 + kt) * 512) + slot * 8 + j0) = *(const ushort4*)hv;
  }
#undef LOADF
#undef CONSUME

  // ---- step A (no Sf dependency — runs while other waves still gather) ----
  const int base = wid;
  const h8 hz = {(_Float16)0.f, (_Float16)0.f, (_Float16)0.f, (_Float16)0.f,
                 (_Float16)0.f, (_Float16)0.f, (_Float16)0.f, (_Float16)0.f};
  f4v gh[2][3], gi[2][3];
#pragma unroll
  for (int m = 0; m < 2; ++m)
#pragma unroll
    for (int gg = 0; gg < 3; ++gg) {
      gh[m][gg] = (f4v){0.f, 0.f, 0.f, 0.f};
      gi[m][gg] = (f4v){0.f, 0.f, 0.f, 0.f};
    }
#pragma unroll
  for (int kt = 0; kt < 4; ++kt) {
    h8 a0 = *(const h8*)(nsf + ((size_t)mt0 * 4 + kt) * 512 + lane * 8);
    h8 a1 = has1 ? *(const h8*)(nsf + ((size_t)(mt0 + 1) * 4 + kt) * 512 + lane * 8) : hz;
#pragma unroll
    for (int gg = 0; gg < 3; ++gg) {
      h8 b = *(const h8*)(Wh16 + ((size_t)(base + 8 * gg) * 4 + kt) * 512 + lane * 8);
      gh[0][gg] = __builtin_amdgcn_mfma_f32_16x16x32_f16(a0, b, gh[0][gg], 0, 0, 0);
      gh[1][gg] = __builtin_amdgcn_mfma_f32_16x16x32_f16(a1, b, gh[1][gg], 0, 0, 0);
    }
  }

  __syncthreads();

  // ---- step B: gi = S @ Gcat.T (K=512), A from swizzled LDS ----
#pragma unroll
  for (int kt = 0; kt < 16; ++kt) {
    const int slot = lane ^ (kt & 7);
    h8 a0 = *(const h8*)(sfl + (0 * 16 + kt) * 512 + slot * 8);
    h8 a1 = has1 ? *(const h8*)(sfl + (1 * 16 + kt) * 512 + slot * 8) : hz;
#pragma unroll
    for (int gg = 0; gg < 3; ++gg) {
      h8 b = *(const h8*)(G16 + ((size_t)(base + 8 * gg) * 16 + kt) * 512 + lane * 8);
      gi[0][gg] = __builtin_amdgcn_mfma_f32_16x16x32_f16(a0, b, gi[0][gg], 0, 0, 0);
      gi[1][gg] = __builtin_amdgcn_mfma_f32_16x16x32_f16(a1, b, gi[1][gg], 0, 0, 0);
    }
  }

  // ---- epilogue ----
  const int c0 = lane & 15, rB = (lane >> 4) * 4;
  const int d = base * 16 + c0;
  const float vf0 = vf[d], vf1 = vf[128 + d], vf2 = vf[256 + d];
  const float vr0 = vr[d], vr1 = vr[128 + d], vr2 = vr[256 + d];
  const float bi0 = b_ih[d], bi1 = b_ih[128 + d], bi2 = b_ih[256 + d];
  const float bh0 = b_hh[d], bh1 = b_hh[128 + d], bh2 = b_hh[256 + d];
#pragma unroll
  for (int m = 0; m < 2; ++m) {
    if (m == 1 && !has1) continue;
    const int mt = mt0 + m;
#pragma unroll
    for (int reg = 0; reg < 4; ++reg) {
      int row = mt * 16 + rB + reg;
      float idg = (float)(off[row + 1] - off[row]);
      float odg = (float)(off[NN + row + 1] - off[NN + row]);
      float gr = gi[m][0][reg] + idg * vf0 + odg * vr0 + bi0;
      float gz = gi[m][1][reg] + idg * vf1 + odg * vr1 + bi1;
      float gn = gi[m][2][reg] + idg * vf2 + odg * vr2 + bi2;
      float hr = gh[m][0][reg] + bh0;
      float hzv = gh[m][1][reg] + bh1;
      float hn = gh[m][2][reg] + bh2;
      float rg = 1.f / (1.f + __expf(-(gr + hr)));
      float zg = 1.f / (1.f + __expf(-(gz + hzv)));
      float ng = tanhf(gn + rg * hn);
      float h = ns[(size_t)row * 128 + d];
      out[(size_t)row * 128 + d] = (1.f - zg) * ng + zg * h;
    }
  }
}

// ---------------- launch ----------------
extern "C" void kernel_launch(void* const* d_in, const int* in_sizes, int n_in,
                              void* d_out, int out_size, void* d_ws, size_t ws_size,
                              hipStream_t stream) {
  const float* ns   = (const float*)d_in[0];
  const int* from   = (const int*)d_in[1];
  const int* to     = (const int*)d_in[2];
  const float* Wf1  = (const float*)d_in[3];
  const float* bf1  = (const float*)d_in[4];
  const float* Wf2  = (const float*)d_in[5];
  const float* bf2  = (const float*)d_in[6];
  const float* Wr1  = (const float*)d_in[7];
  const float* br1  = (const float*)d_in[8];
  const float* Wr2  = (const float*)d_in[9];
  const float* br2  = (const float*)d_in[10];
  const float* W_ih = (const float*)d_in[11];
  const float* W_hh = (const float*)d_in[12];
  const float* b_ih = (const float*)d_in[13];
  const float* b_hh = (const float*)d_in[14];
  float* out = (float*)d_out;

  // workspace layout (256B aligned)
  char* w = (char*)d_ws;
  u16*   Wc16    = (u16*)(w + 0);            // 262144
  float* biascat = (float*)(w + 262144);     // 4096
  u16*   G16     = (u16*)(w + 266240);       // 393216
  u16*   Wh16    = (u16*)(w + 659456);       // 98304
  float* vf      = (float*)(w + 757760);     // 1536
  float* vr      = (float*)(w + 759296);     // 1536
  int*   cnt     = (int*)(w + 760832);       // 400128
  int*   off     = (int*)(w + 1160960);      // 400128
  int*   cur     = (int*)(w + 1561088);      // 400128
  int*   bsum    = (int*)(w + 1961216);      // 512
  int*   nbr     = (int*)(w + 1961728);      // 4096000
  u16*   nsf     = (u16*)(w + 6057728);      // 12800000
  u16*   Tin     = (u16*)(w + 18857728);     // 25600000
  u16*   Tout    = (u16*)(w + 44457728);     // 25600000
  u16*   Tnode   = (u16*)(w + 70057728);     // 51200000
  // total 121257728 bytes

  hipMemsetAsync(cnt, 0, 400000, stream);

  k_prep<<<6599, 256, 0, stream>>>(Wf1, bf1, Wr1, br1, W_ih, Wf2, Wr2, W_hh,
                                   bf2, br2, ns, from, to, Wc16, biascat, G16,
                                   Wh16, vf, vr, nsf, cnt);

  k_scanA<<<SCAN_BLOCKS, 256, 0, stream>>>(cnt, bsum);
  k_scanC<<<SCAN_BLOCKS, 256, 0, stream>>>(cnt, bsum, off, cur);

  k_projfill<<<5128, 256, 0, stream>>>(nsf, Wc16, biascat, Tin, Tnode, Tout,
                                       from, to, cur, nbr);

  k_fused<<<1563, 512, 0, stream>>>(Tin, Tnode, Tout, nbr, off, nsf, G16, Wh16,
                                    ns, b_ih, b_hh, vf, vr, out);
}